// Round 1
// baseline (301.328 us; speedup 1.0000x reference)
//
#include <hip/hip_runtime.h>
#include <hip/hip_bf16.h>
#include <cstdint>
#include <cstddef>

#define BDIM 32768
#define IDIM 512
#define ODIM 512
#define KDIM 1024   // I+O
#define NDIM 2048   // 4*O

typedef __attribute__((ext_vector_type(8))) __bf16 bf16x8;
typedef __attribute__((ext_vector_type(4))) float f32x4;
typedef __attribute__((ext_vector_type(8))) unsigned short u16x8;

__device__ __forceinline__ unsigned short f2bf(float x) {
  union { float f; uint32_t u; } v; v.f = x;
  uint32_t r = v.u + 0x7FFFu + ((v.u >> 16) & 1u);  // RNE
  return (unsigned short)(r >> 16);
}

__device__ __forceinline__ float bf2f(unsigned short s) {
  union { uint32_t u; float f; } v; v.u = ((uint32_t)s) << 16;
  return v.f;
}

// ---------------- pack kernels: f32 -> bf16 ----------------

__global__ __launch_bounds__(256) void pack_a_kernel(const float* __restrict__ in,
                                                     const float* __restrict__ h,
                                                     unsigned short* __restrict__ A) {
  size_t t = (size_t)blockIdx.x * 256 + threadIdx.x;  // each thread: 8 elems
  size_t e = t * 8;
  size_t b = e >> 10;           // row (batch)
  int col = (int)(e & 1023);    // col in [0,1024)
  const float* src = (col < IDIM) ? (in + b * IDIM + col)
                                  : (h + b * ODIM + (col - IDIM));
  float4 v0 = ((const float4*)src)[0];
  float4 v1 = ((const float4*)src)[1];
  u16x8 r;
  r[0] = f2bf(v0.x); r[1] = f2bf(v0.y); r[2] = f2bf(v0.z); r[3] = f2bf(v0.w);
  r[4] = f2bf(v1.x); r[5] = f2bf(v1.y); r[6] = f2bf(v1.z); r[7] = f2bf(v1.w);
  *(u16x8*)(A + e) = r;
}

__global__ __launch_bounds__(256) void pack_w_kernel(const float* __restrict__ Wsrc,
                                                     unsigned short* __restrict__ Wb) {
  size_t t = (size_t)blockIdx.x * 256 + threadIdx.x;
  size_t e = t * 8;
  float4 v0 = ((const float4*)(Wsrc + e))[0];
  float4 v1 = ((const float4*)(Wsrc + e))[1];
  u16x8 r;
  r[0] = f2bf(v0.x); r[1] = f2bf(v0.y); r[2] = f2bf(v0.z); r[3] = f2bf(v0.w);
  r[4] = f2bf(v1.x); r[5] = f2bf(v1.y); r[6] = f2bf(v1.z); r[7] = f2bf(v1.w);
  *(u16x8*)(Wb + e) = r;
}

// ---------------- GEMM: C[m,n] = sum_k A[m,k] * Bt[n,k], bf16 in, bf16 out ----------------
// m97 structure: 128x128 tile, BK=64, 4 waves (2x2), 4x4 16x16 frags per wave,
// global_load_lds width=16, 2 barriers per K-step.

#define TM 128
#define TN 128
#define TK 64

__global__ __launch_bounds__(256) void gemm_kernel(const unsigned short* __restrict__ A,
                                                   const unsigned short* __restrict__ Bt,
                                                   unsigned short* __restrict__ Cz) {
  __shared__ unsigned short As[TM][TK];  // 16 KB
  __shared__ unsigned short Bs[TN][TK];  // 16 KB
  const int tid = threadIdx.x;
  const int wave = tid >> 6;
  const int lane = tid & 63;
  const int m0 = blockIdx.x * TM;
  const int n0 = blockIdx.y * TN;
  const int wm = (wave >> 1) * 64;
  const int wn = (wave & 1) * 64;

  f32x4 acc[4][4] = {};

  const int r_in_chunk = lane >> 3;       // 0..7
  const int kc = (lane & 7) * 8;          // k element offset within tile

  for (int kt = 0; kt < KDIM / TK; ++kt) {
    const int k0 = kt * TK;
    __syncthreads();
#pragma unroll
    for (int i = 0; i < 4; ++i) {
      const int chunk = i * 4 + wave;                 // 0..15, wave-uniform
      const int row = chunk * 8 + r_in_chunk;         // 0..127
      __builtin_amdgcn_global_load_lds(
          (const __attribute__((address_space(1))) void*)(A + (size_t)(m0 + row) * KDIM + k0 + kc),
          (__attribute__((address_space(3))) void*)((char*)(&As[0][0]) + chunk * 1024),
          16, 0, 0);
      __builtin_amdgcn_global_load_lds(
          (const __attribute__((address_space(1))) void*)(Bt + (size_t)(n0 + row) * KDIM + k0 + kc),
          (__attribute__((address_space(3))) void*)((char*)(&Bs[0][0]) + chunk * 1024),
          16, 0, 0);
    }
    __syncthreads();
#pragma unroll
    for (int kk = 0; kk < TK; kk += 32) {
      bf16x8 af[4], bfr[4];
#pragma unroll
      for (int mi = 0; mi < 4; ++mi)
        af[mi] = *(const bf16x8*)&As[wm + mi * 16 + (lane & 15)][kk + (lane >> 4) * 8];
#pragma unroll
      for (int ni = 0; ni < 4; ++ni)
        bfr[ni] = *(const bf16x8*)&Bs[wn + ni * 16 + (lane & 15)][kk + (lane >> 4) * 8];
#pragma unroll
      for (int mi = 0; mi < 4; ++mi)
#pragma unroll
        for (int ni = 0; ni < 4; ++ni)
          acc[mi][ni] = __builtin_amdgcn_mfma_f32_16x16x32_bf16(af[mi], bfr[ni], acc[mi][ni], 0, 0, 0);
    }
  }

  // epilogue: C/D layout col = lane&15, row = (lane>>4)*4 + r
#pragma unroll
  for (int mi = 0; mi < 4; ++mi) {
#pragma unroll
    for (int ni = 0; ni < 4; ++ni) {
#pragma unroll
      for (int r = 0; r < 4; ++r) {
        const int row = m0 + wm + mi * 16 + (lane >> 4) * 4 + r;
        const int col = n0 + wn + ni * 16 + (lane & 15);
        Cz[(size_t)row * NDIM + col] = f2bf(acc[mi][ni][r]);
      }
    }
  }
}

// ---------------- LayerNorm + gates ----------------
// one wave per row; row of 2048 staged in LDS (f32); shfl reduce mean/var

__global__ __launch_bounds__(256) void ln_gate_kernel(const unsigned short* __restrict__ z,
                                                      const float* __restrict__ c,
                                                      const float* __restrict__ gamma,
                                                      const float* __restrict__ beta,
                                                      float* __restrict__ out) {
  __shared__ float rowbuf[4][NDIM];  // 32 KB
  const int wave = threadIdx.x >> 6;
  const int lane = threadIdx.x & 63;
  const int row = blockIdx.x * 4 + wave;
  const unsigned short* zr = z + (size_t)row * NDIM;

  float s = 0.f, ss = 0.f;
#pragma unroll
  for (int j = 0; j < 4; ++j) {
    const int chunk = j * 64 + lane;  // 0..255, covers 2048 elems in 8-elem chunks
    u16x8 v = *(const u16x8*)(zr + chunk * 8);
    float f[8];
#pragma unroll
    for (int i2 = 0; i2 < 8; ++i2) {
      f[i2] = bf2f(v[i2]);
      s += f[i2];
      ss += f[i2] * f[i2];
    }
    float4* dst = (float4*)&rowbuf[wave][chunk * 8];
    dst[0] = make_float4(f[0], f[1], f[2], f[3]);
    dst[1] = make_float4(f[4], f[5], f[6], f[7]);
  }
#pragma unroll
  for (int off = 32; off > 0; off >>= 1) {
    s += __shfl_xor(s, off, 64);
    ss += __shfl_xor(ss, off, 64);
  }
  const float mean = s * (1.f / (float)NDIM);
  const float var = ss * (1.f / (float)NDIM) - mean * mean;
  const float inv = rsqrtf(var + 1e-5f);

  float* out_o = out + (size_t)row * ODIM;
  float* out_c = out + (size_t)BDIM * ODIM + (size_t)row * ODIM;
  const float* crow = c + (size_t)row * ODIM;

#pragma unroll
  for (int j = 0; j < 8; ++j) {
    const int o = j * 64 + lane;
    float zn[4];
#pragma unroll
    for (int g = 0; g < 4; ++g) {
      float v = (rowbuf[wave][g * ODIM + o] - mean) * inv;
      zn[g] = v * gamma[g * ODIM + o] + beta[g * ODIM + o];
    }
    const float fg = 1.f / (1.f + expf(-zn[0]));
    const float ig = 1.f / (1.f + expf(-zn[1]));
    const float og = 1.f / (1.f + expf(-zn[2]));
    const float x = zn[3];
    const float hs = 0.5f * x * (1.f + erff(x * 0.70710678118654752f));
    const float cc = fg * crow[o] + ig * hs;
    out_c[o] = cc;
    out_o[o] = og * cc;
  }
}

// ---------------- launch ----------------

extern "C" void kernel_launch(void* const* d_in, const int* in_sizes, int n_in,
                              void* d_out, int out_size, void* d_ws, size_t ws_size,
                              hipStream_t stream) {
  const float* input = (const float*)d_in[0];
  const float* h     = (const float*)d_in[1];
  const float* c     = (const float*)d_in[2];
  const float* W     = (const float*)d_in[3];
  const float* gamma = (const float*)d_in[4];
  const float* beta  = (const float*)d_in[5];

  unsigned short* A  = (unsigned short*)d_ws;                 // [32768,1024] bf16
  unsigned short* Wb = A + (size_t)BDIM * KDIM;               // [2048,1024] bf16
  unsigned short* z  = Wb + (size_t)NDIM * KDIM;              // [32768,2048] bf16
  float* out = (float*)d_out;

  pack_a_kernel<<<(BDIM * KDIM / 8) / 256, 256, 0, stream>>>(input, h, A);
  pack_w_kernel<<<(NDIM * KDIM / 8) / 256, 256, 0, stream>>>(W, Wb);
  dim3 ggrid(BDIM / TM, NDIM / TN);
  gemm_kernel<<<ggrid, 256, 0, stream>>>(A, Wb, z);
  ln_gate_kernel<<<BDIM / 4, 256, 0, stream>>>(z, c, gamma, beta, out);
}

// Round 3
// 271.295 us; speedup vs baseline: 1.1107x; 1.1107x over previous
//
#include <hip/hip_runtime.h>
#include <hip/hip_bf16.h>
#include <cstdint>
#include <cstddef>

#define BDIM 32768
#define IDIM 512
#define ODIM 512
#define KDIM 1024   // I+O
#define NDIM 2048   // 4*O

typedef __attribute__((ext_vector_type(8))) __bf16 bf16x8;
typedef __attribute__((ext_vector_type(4))) float f32x4;
typedef __attribute__((ext_vector_type(8))) unsigned short u16x8;

__device__ __forceinline__ unsigned short f2bf(float x) {
  union { float f; uint32_t u; } v; v.f = x;
  uint32_t r = v.u + 0x7FFFu + ((v.u >> 16) & 1u);  // RNE
  return (unsigned short)(r >> 16);
}

__device__ __forceinline__ float bf2f(unsigned short s) {
  union { uint32_t u; float f; } v; v.u = ((uint32_t)s) << 16;
  return v.f;
}

// ---------------- pack kernels: f32 -> bf16 ----------------

__global__ __launch_bounds__(256) void pack_a_kernel(const float* __restrict__ in,
                                                     const float* __restrict__ h,
                                                     unsigned short* __restrict__ A) {
  size_t t = (size_t)blockIdx.x * 256 + threadIdx.x;  // each thread: 8 elems
  size_t e = t * 8;
  size_t b = e >> 10;           // row (batch)
  int col = (int)(e & 1023);    // col in [0,1024)
  const float* src = (col < IDIM) ? (in + b * IDIM + col)
                                  : (h + b * ODIM + (col - IDIM));
  float4 v0 = ((const float4*)src)[0];
  float4 v1 = ((const float4*)src)[1];
  u16x8 r;
  r[0] = f2bf(v0.x); r[1] = f2bf(v0.y); r[2] = f2bf(v0.z); r[3] = f2bf(v0.w);
  r[4] = f2bf(v1.x); r[5] = f2bf(v1.y); r[6] = f2bf(v1.z); r[7] = f2bf(v1.w);
  *(u16x8*)(A + e) = r;
}

__global__ __launch_bounds__(256) void pack_w_kernel(const float* __restrict__ Wsrc,
                                                     unsigned short* __restrict__ Wb) {
  size_t t = (size_t)blockIdx.x * 256 + threadIdx.x;
  size_t e = t * 8;
  float4 v0 = ((const float4*)(Wsrc + e))[0];
  float4 v1 = ((const float4*)(Wsrc + e))[1];
  u16x8 r;
  r[0] = f2bf(v0.x); r[1] = f2bf(v0.y); r[2] = f2bf(v0.z); r[3] = f2bf(v0.w);
  r[4] = f2bf(v1.x); r[5] = f2bf(v1.y); r[6] = f2bf(v1.z); r[7] = f2bf(v1.w);
  *(u16x8*)(Wb + e) = r;
}

// ---------------- GEMM: 256x256 tile, BK=32, ring-4 LDS, counted vmcnt ----------------
// 8 waves (2M x 4N), per-wave 128x64 output = acc[8][4] f32x4.
// LDS: 4 buffers x (A[256][32] 16KB + B[256][32] 16KB) = 128KB dynamic.
// Swizzle (involution): physical chunk = logical chunk ^ ((row>>2)&3), 16B chunks.
// Applied on global SOURCE (linear global_load_lds dest) and on ds_read address.
// NOTE: global_load_lds is ALWAYS issued with imm offset 0; K-advance is done
// via C++ pointer arithmetic (offset-immediate HW semantics not trusted).

#define BUFSZ 32768
#define ABYTES 16384

#define BAR() do { asm volatile("" ::: "memory"); __builtin_amdgcn_s_barrier(); asm volatile("" ::: "memory"); } while (0)
#define VMW(n) asm volatile("s_waitcnt vmcnt(" #n ")" ::: "memory")

__device__ __forceinline__ void gll16(const unsigned short* src, char* ldsdst) {
  __builtin_amdgcn_global_load_lds(
      (const __attribute__((address_space(1))) void*)src,
      (__attribute__((address_space(3))) void*)ldsdst, 16, 0, 0);
}

template<int BUF, int VM, bool STG, int TO>
__device__ __forceinline__ void tile_body(char* smem,
                                          const unsigned short* sA0, const unsigned short* sA1,
                                          const unsigned short* sB0, const unsigned short* sB1,
                                          int wave1024, int aoff, int boff,
                                          f32x4 (&acc)[8][4]) {
  char* const Ab = smem + BUF * BUFSZ;
  char* const Bb = Ab + ABYTES;
  constexpr int DB = ((BUF + 3) & 3) * BUFSZ;

  if (VM == 8)      VMW(8);
  else if (VM == 4) VMW(4);
  else              VMW(0);
  BAR();

  // ---- phase 0: A frags 0-3 + all B frags; stage part 0 of tile BUF+3 ----
  bf16x8 x0 = *(const bf16x8*)(Ab + aoff + 0 * 1024);
  bf16x8 x1 = *(const bf16x8*)(Ab + aoff + 1 * 1024);
  bf16x8 x2 = *(const bf16x8*)(Ab + aoff + 2 * 1024);
  bf16x8 x3 = *(const bf16x8*)(Ab + aoff + 3 * 1024);
  bf16x8 b0 = *(const bf16x8*)(Bb + boff + 0 * 1024);
  bf16x8 b1 = *(const bf16x8*)(Bb + boff + 1 * 1024);
  bf16x8 b2 = *(const bf16x8*)(Bb + boff + 2 * 1024);
  bf16x8 b3 = *(const bf16x8*)(Bb + boff + 3 * 1024);
  if (STG) {
    gll16(sA0 + TO * 32, smem + DB + wave1024);
    gll16(sB0 + TO * 32, smem + DB + ABYTES + wave1024);
  }
  BAR();
  __builtin_amdgcn_sched_barrier(0);
  __builtin_amdgcn_s_setprio(1);
  acc[0][0] = __builtin_amdgcn_mfma_f32_16x16x32_bf16(x0, b0, acc[0][0], 0, 0, 0);
  acc[0][1] = __builtin_amdgcn_mfma_f32_16x16x32_bf16(x0, b1, acc[0][1], 0, 0, 0);
  acc[0][2] = __builtin_amdgcn_mfma_f32_16x16x32_bf16(x0, b2, acc[0][2], 0, 0, 0);
  acc[0][3] = __builtin_amdgcn_mfma_f32_16x16x32_bf16(x0, b3, acc[0][3], 0, 0, 0);
  acc[1][0] = __builtin_amdgcn_mfma_f32_16x16x32_bf16(x1, b0, acc[1][0], 0, 0, 0);
  acc[1][1] = __builtin_amdgcn_mfma_f32_16x16x32_bf16(x1, b1, acc[1][1], 0, 0, 0);
  acc[1][2] = __builtin_amdgcn_mfma_f32_16x16x32_bf16(x1, b2, acc[1][2], 0, 0, 0);
  acc[1][3] = __builtin_amdgcn_mfma_f32_16x16x32_bf16(x1, b3, acc[1][3], 0, 0, 0);
  acc[2][0] = __builtin_amdgcn_mfma_f32_16x16x32_bf16(x2, b0, acc[2][0], 0, 0, 0);
  acc[2][1] = __builtin_amdgcn_mfma_f32_16x16x32_bf16(x2, b1, acc[2][1], 0, 0, 0);
  acc[2][2] = __builtin_amdgcn_mfma_f32_16x16x32_bf16(x2, b2, acc[2][2], 0, 0, 0);
  acc[2][3] = __builtin_amdgcn_mfma_f32_16x16x32_bf16(x2, b3, acc[2][3], 0, 0, 0);
  acc[3][0] = __builtin_amdgcn_mfma_f32_16x16x32_bf16(x3, b0, acc[3][0], 0, 0, 0);
  acc[3][1] = __builtin_amdgcn_mfma_f32_16x16x32_bf16(x3, b1, acc[3][1], 0, 0, 0);
  acc[3][2] = __builtin_amdgcn_mfma_f32_16x16x32_bf16(x3, b2, acc[3][2], 0, 0, 0);
  acc[3][3] = __builtin_amdgcn_mfma_f32_16x16x32_bf16(x3, b3, acc[3][3], 0, 0, 0);
  __builtin_amdgcn_s_setprio(0);
  __builtin_amdgcn_sched_barrier(0);
  BAR();

  // ---- phase 1: A frags 4-7; stage part 1 of tile BUF+3 ----
  x0 = *(const bf16x8*)(Ab + aoff + 4 * 1024);
  x1 = *(const bf16x8*)(Ab + aoff + 5 * 1024);
  x2 = *(const bf16x8*)(Ab + aoff + 6 * 1024);
  x3 = *(const bf16x8*)(Ab + aoff + 7 * 1024);
  if (STG) {
    gll16(sA1 + TO * 32, smem + DB + 8192 + wave1024);
    gll16(sB1 + TO * 32, smem + DB + ABYTES + 8192 + wave1024);
  }
  BAR();
  __builtin_amdgcn_sched_barrier(0);
  __builtin_amdgcn_s_setprio(1);
  acc[4][0] = __builtin_amdgcn_mfma_f32_16x16x32_bf16(x0, b0, acc[4][0], 0, 0, 0);
  acc[4][1] = __builtin_amdgcn_mfma_f32_16x16x32_bf16(x0, b1, acc[4][1], 0, 0, 0);
  acc[4][2] = __builtin_amdgcn_mfma_f32_16x16x32_bf16(x0, b2, acc[4][2], 0, 0, 0);
  acc[4][3] = __builtin_amdgcn_mfma_f32_16x16x32_bf16(x0, b3, acc[4][3], 0, 0, 0);
  acc[5][0] = __builtin_amdgcn_mfma_f32_16x16x32_bf16(x1, b0, acc[5][0], 0, 0, 0);
  acc[5][1] = __builtin_amdgcn_mfma_f32_16x16x32_bf16(x1, b1, acc[5][1], 0, 0, 0);
  acc[5][2] = __builtin_amdgcn_mfma_f32_16x16x32_bf16(x1, b2, acc[5][2], 0, 0, 0);
  acc[5][3] = __builtin_amdgcn_mfma_f32_16x16x32_bf16(x1, b3, acc[5][3], 0, 0, 0);
  acc[6][0] = __builtin_amdgcn_mfma_f32_16x16x32_bf16(x2, b0, acc[6][0], 0, 0, 0);
  acc[6][1] = __builtin_amdgcn_mfma_f32_16x16x32_bf16(x2, b1, acc[6][1], 0, 0, 0);
  acc[6][2] = __builtin_amdgcn_mfma_f32_16x16x32_bf16(x2, b2, acc[6][2], 0, 0, 0);
  acc[6][3] = __builtin_amdgcn_mfma_f32_16x16x32_bf16(x2, b3, acc[6][3], 0, 0, 0);
  acc[7][0] = __builtin_amdgcn_mfma_f32_16x16x32_bf16(x3, b0, acc[7][0], 0, 0, 0);
  acc[7][1] = __builtin_amdgcn_mfma_f32_16x16x32_bf16(x3, b1, acc[7][1], 0, 0, 0);
  acc[7][2] = __builtin_amdgcn_mfma_f32_16x16x32_bf16(x3, b2, acc[7][2], 0, 0, 0);
  acc[7][3] = __builtin_amdgcn_mfma_f32_16x16x32_bf16(x3, b3, acc[7][3], 0, 0, 0);
  __builtin_amdgcn_s_setprio(0);
  __builtin_amdgcn_sched_barrier(0);
  // no trailing barrier: next tile's top barrier covers it
}

__global__ __launch_bounds__(512, 2) void gemm_kernel(const unsigned short* __restrict__ A,
                                                      const unsigned short* __restrict__ Bt,
                                                      unsigned short* __restrict__ Cz) {
  extern __shared__ char smem[];
  const int tid = threadIdx.x;
  const int wave = tid >> 6;
  const int lane = tid & 63;

  // XCD swizzle: each XCD gets a 16-mtile x 8-ntile chunk (B panel L2-resident)
  const int bid = blockIdx.x;                       // 0..1023
  const int swz = (bid & 7) * 128 + (bid >> 3);
  const int m0 = (swz >> 3) * 256;
  const int n0 = (swz & 7) * 256;

  const int wm = (wave >> 2) * 128;   // 2 M-wave-rows
  const int wn = (wave & 3) * 64;     // 4 N-wave-cols
  const int lrow = lane & 15;
  const int cswz16 = (((lane >> 4) ^ (lrow >> 2)) & 3) * 16;
  const int aoff = (wm + lrow) * 64 + cswz16;
  const int boff = (wn + lrow) * 64 + cswz16;
  const int wave1024 = wave * 1024;

  // staging source pointers (pre-swizzled global addresses)
  const int r0 = tid >> 2;
  const int r1 = r0 + 128;
  const int c0 = (tid & 3) ^ ((r0 >> 2) & 3);
  const int c1 = (tid & 3) ^ ((r1 >> 2) & 3);
  const unsigned short* sA0 = A  + (size_t)(m0 + r0) * KDIM + c0 * 8;
  const unsigned short* sA1 = A  + (size_t)(m0 + r1) * KDIM + c1 * 8;
  const unsigned short* sB0 = Bt + (size_t)(n0 + r0) * KDIM + c0 * 8;
  const unsigned short* sB1 = Bt + (size_t)(n0 + r1) * KDIM + c1 * 8;

  f32x4 acc[8][4] = {};

  // prologue: stage tiles 0,1,2 (12 loads/thread, grouped by tile for vmcnt FIFO)
  gll16(sA0,      smem + 0 * BUFSZ + wave1024);
  gll16(sB0,      smem + 0 * BUFSZ + ABYTES + wave1024);
  gll16(sA1,      smem + 0 * BUFSZ + 8192 + wave1024);
  gll16(sB1,      smem + 0 * BUFSZ + ABYTES + 8192 + wave1024);
  gll16(sA0 + 32, smem + 1 * BUFSZ + wave1024);
  gll16(sB0 + 32, smem + 1 * BUFSZ + ABYTES + wave1024);
  gll16(sA1 + 32, smem + 1 * BUFSZ + 8192 + wave1024);
  gll16(sB1 + 32, smem + 1 * BUFSZ + ABYTES + 8192 + wave1024);
  gll16(sA0 + 64, smem + 2 * BUFSZ + wave1024);
  gll16(sB0 + 64, smem + 2 * BUFSZ + ABYTES + wave1024);
  gll16(sA1 + 64, smem + 2 * BUFSZ + 8192 + wave1024);
  gll16(sB1 + 64, smem + 2 * BUFSZ + ABYTES + 8192 + wave1024);

  // main loop: tiles 0..27 (stage tiles 3..30)
  for (int t4 = 0; t4 < 28; t4 += 4) {
    tile_body<0, 8, true, 3>(smem, sA0, sA1, sB0, sB1, wave1024, aoff, boff, acc);
    tile_body<1, 8, true, 4>(smem, sA0, sA1, sB0, sB1, wave1024, aoff, boff, acc);
    tile_body<2, 8, true, 5>(smem, sA0, sA1, sB0, sB1, wave1024, aoff, boff, acc);
    tile_body<3, 8, true, 6>(smem, sA0, sA1, sB0, sB1, wave1024, aoff, boff, acc);
    sA0 += 128; sA1 += 128; sB0 += 128; sB1 += 128;
  }
  // tiles 28..31 (tile 28 stages tile 31; then taper vmcnt 8 -> 4 -> 0)
  tile_body<0, 8, true,  3>(smem, sA0, sA1, sB0, sB1, wave1024, aoff, boff, acc);
  tile_body<1, 8, false, 0>(smem, sA0, sA1, sB0, sB1, wave1024, aoff, boff, acc);
  tile_body<2, 4, false, 0>(smem, sA0, sA1, sB0, sB1, wave1024, aoff, boff, acc);
  tile_body<3, 0, false, 0>(smem, sA0, sA1, sB0, sB1, wave1024, aoff, boff, acc);

  // epilogue: C/D layout col = lane&15, row = (lane>>4)*4 + r
#pragma unroll
  for (int mi = 0; mi < 8; ++mi) {
#pragma unroll
    for (int ni = 0; ni < 4; ++ni) {
#pragma unroll
      for (int r = 0; r < 4; ++r) {
        const int row = m0 + wm + mi * 16 + (lane >> 4) * 4 + r;
        const int col = n0 + wn + ni * 16 + lrow;
        Cz[(size_t)row * NDIM + col] = f2bf(acc[mi][ni][r]);
      }
    }
  }
}

// ---------------- LayerNorm + gates ----------------

__global__ __launch_bounds__(256) void ln_gate_kernel(const unsigned short* __restrict__ z,
                                                      const float* __restrict__ c,
                                                      const float* __restrict__ gamma,
                                                      const float* __restrict__ beta,
                                                      float* __restrict__ out) {
  __shared__ float rowbuf[4][NDIM];  // 32 KB
  const int wave = threadIdx.x >> 6;
  const int lane = threadIdx.x & 63;
  const int row = blockIdx.x * 4 + wave;
  const unsigned short* zr = z + (size_t)row * NDIM;

  float s = 0.f, ss = 0.f;
#pragma unroll
  for (int j = 0; j < 4; ++j) {
    const int chunk = j * 64 + lane;
    u16x8 v = *(const u16x8*)(zr + chunk * 8);
    float f[8];
#pragma unroll
    for (int i2 = 0; i2 < 8; ++i2) {
      f[i2] = bf2f(v[i2]);
      s += f[i2];
      ss += f[i2] * f[i2];
    }
    float4* dst = (float4*)&rowbuf[wave][chunk * 8];
    dst[0] = make_float4(f[0], f[1], f[2], f[3]);
    dst[1] = make_float4(f[4], f[5], f[6], f[7]);
  }
#pragma unroll
  for (int off = 32; off > 0; off >>= 1) {
    s += __shfl_xor(s, off, 64);
    ss += __shfl_xor(ss, off, 64);
  }
  const float mean = s * (1.f / (float)NDIM);
  const float var = ss * (1.f / (float)NDIM) - mean * mean;
  const float inv = rsqrtf(var + 1e-5f);

  float* out_o = out + (size_t)row * ODIM;
  float* out_c = out + (size_t)BDIM * ODIM + (size_t)row * ODIM;
  const float* crow = c + (size_t)row * ODIM;

#pragma unroll
  for (int j = 0; j < 8; ++j) {
    const int o = j * 64 + lane;
    float zn[4];
#pragma unroll
    for (int g = 0; g < 4; ++g) {
      float v = (rowbuf[wave][g * ODIM + o] - mean) * inv;
      zn[g] = v * gamma[g * ODIM + o] + beta[g * ODIM + o];
    }
    const float fg = 1.f / (1.f + expf(-zn[0]));
    const float ig = 1.f / (1.f + expf(-zn[1]));
    const float og = 1.f / (1.f + expf(-zn[2]));
    const float x = zn[3];
    const float hs = 0.5f * x * (1.f + erff(x * 0.70710678118654752f));
    const float cc = fg * crow[o] + ig * hs;
    out_c[o] = cc;
    out_o[o] = og * cc;
  }
}

// ---------------- launch ----------------

extern "C" void kernel_launch(void* const* d_in, const int* in_sizes, int n_in,
                              void* d_out, int out_size, void* d_ws, size_t ws_size,
                              hipStream_t stream) {
  const float* input = (const float*)d_in[0];
  const float* h     = (const float*)d_in[1];
  const float* c     = (const float*)d_in[2];
  const float* W     = (const float*)d_in[3];
  const float* gamma = (const float*)d_in[4];
  const float* beta  = (const float*)d_in[5];

  unsigned short* A  = (unsigned short*)d_ws;                 // [32768,1024] bf16
  unsigned short* Wb = A + (size_t)BDIM * KDIM;               // [2048,1024] bf16
  unsigned short* z  = Wb + (size_t)NDIM * KDIM;              // [32768,2048] bf16
  float* out = (float*)d_out;

  hipFuncSetAttribute((const void*)gemm_kernel,
                      hipFuncAttributeMaxDynamicSharedMemorySize, 131072);

  pack_a_kernel<<<(BDIM * KDIM / 8) / 256, 256, 0, stream>>>(input, h, A);
  pack_w_kernel<<<(NDIM * KDIM / 8) / 256, 256, 0, stream>>>(W, Wb);
  gemm_kernel<<<dim3((BDIM / 256) * (NDIM / 256)), 512, 131072, stream>>>(A, Wb, z);
  ln_gate_kernel<<<BDIM / 4, 256, 0, stream>>>(z, c, gamma, beta, out);
}